// Round 1
// baseline (253.831 us; speedup 1.0000x reference)
//
#include <hip/hip_runtime.h>

// UnitaryBranching: maps = product of path-digit unitaries (via 127-entry
// binary-tree table), steps = 24 - 2*commonPrefixLen of padded path words.
// N_POS=4096, T=12, DIM=64, BF=2. Only primitives[0:2] are used by the ref.

#define NPOS 4096
#define TLEN 12

// C = P @ B, 64x64 f32, 256 threads, 4x4 tile per thread.
// P padded [64][65] (per-k column reads land on distinct banks),
// B unpadded [64][64] (row-contiguous float4 reads, 2-way max = free).
__device__ __forceinline__ void mm64(const float P[64][65], const float B[64][64],
                                     float acc[4][4], int t) {
  const int r0 = (t >> 4) << 2, c0 = (t & 15) << 2;
#pragma unroll 8
  for (int k = 0; k < 64; ++k) {
    const float4 bv = *reinterpret_cast<const float4*>(&B[k][c0]);
    const float a0 = P[r0 + 0][k];
    const float a1 = P[r0 + 1][k];
    const float a2 = P[r0 + 2][k];
    const float a3 = P[r0 + 3][k];
    acc[0][0] += a0 * bv.x; acc[0][1] += a0 * bv.y; acc[0][2] += a0 * bv.z; acc[0][3] += a0 * bv.w;
    acc[1][0] += a1 * bv.x; acc[1][1] += a1 * bv.y; acc[1][2] += a1 * bv.z; acc[1][3] += a1 * bv.w;
    acc[2][0] += a2 * bv.x; acc[2][1] += a2 * bv.y; acc[2][2] += a2 * bv.z; acc[2][3] += a2 * bv.w;
    acc[3][0] += a3 * bv.x; acc[3][1] += a3 * bv.y; acc[3][2] += a3 * bv.z; acc[3][3] += a3 * bv.w;
  }
}

// One block per matrix d in {0,1}: E = expm((raw_d - raw_d^T)/1) via the
// reference's scaling-and-squaring (A/2^8, Horner order 12, 8 squarings).
// Writes ext[d] = E^T into tab slot (1+d); block 0 also writes tab[0] = I.
__global__ __launch_bounds__(256) void expm_kernel(const float* __restrict__ raw,
                                                   float* __restrict__ tab) {
  __shared__ float P[64][65];
  __shared__ float Bs[64][64];
  __shared__ float Cs[64][64];
  const int t = threadIdx.x;
  const int d = blockIdx.x;
  const int r0 = (t >> 4) << 2, c0 = (t & 15) << 2;

  // load raw[d] into Cs
#pragma unroll
  for (int i = 0; i < 16; ++i) {
    const int idx = (i << 8) | t;
    Cs[idx >> 6][idx & 63] = raw[d * 4096 + idx];
  }
  __syncthreads();
  // P = (raw - raw^T) / 2^8 ; Bs = I
#pragma unroll
  for (int i = 0; i < 16; ++i) {
    const int idx = (i << 8) | t;
    const int r = idx >> 6, c = idx & 63;
    P[r][c] = (Cs[r][c] - Cs[c][r]) * (1.0f / 256.0f);
    Bs[r][c] = (r == c) ? 1.0f : 0.0f;
  }
  __syncthreads();

  // Horner: for k = 12..1: E = I + (A @ E)/k      (E lives in Bs)
  for (int k = 12; k >= 1; --k) {
    float acc[4][4] = {};
    mm64(P, Bs, acc, t);
#pragma unroll
    for (int i = 0; i < 4; ++i)
      *reinterpret_cast<float4*>(&Cs[r0 + i][c0]) =
          make_float4(acc[i][0], acc[i][1], acc[i][2], acc[i][3]);
    __syncthreads();  // all mm64 reads of Bs done; Cs complete
    const float inv = 1.0f / (float)k;
#pragma unroll
    for (int i = 0; i < 16; ++i) {
      const int idx = (i << 8) | t;
      const int r = idx >> 6, c = idx & 63;
      Bs[r][c] = ((r == c) ? 1.0f : 0.0f) + Cs[r][c] * inv;
    }
    __syncthreads();
  }

  // 8 squarings: E = E @ E
  for (int s = 0; s < 8; ++s) {
#pragma unroll
    for (int i = 0; i < 16; ++i) {
      const int idx = (i << 8) | t;
      P[idx >> 6][idx & 63] = Bs[idx >> 6][idx & 63];
    }
    __syncthreads();
    float acc[4][4] = {};
    mm64(P, Bs, acc, t);
    __syncthreads();  // all reads of Bs done before overwrite
#pragma unroll
    for (int i = 0; i < 4; ++i)
      *reinterpret_cast<float4*>(&Bs[r0 + i][c0]) =
          make_float4(acc[i][0], acc[i][1], acc[i][2], acc[i][3]);
    __syncthreads();
  }

  // tab[1+d] = E^T  (ext[d] = primitives[d]^T)
  float* outp = tab + (size_t)(1 + d) * 4096;
#pragma unroll
  for (int i = 0; i < 16; ++i) {
    const int idx = (i << 8) | t;
    const int r = idx >> 6, c = idx & 63;
    outp[idx] = Bs[c][r];
  }
  if (d == 0) {
#pragma unroll
    for (int i = 0; i < 16; ++i) {
      const int idx = (i << 8) | t;
      const int r = idx >> 6, c = idx & 63;
      tab[idx] = (r == c) ? 1.0f : 0.0f;
    }
  }
}

// Build tree-table level l: tab[(2^l-1)+v] = tab[(2^{l-1}-1)+(v>>1)] @ tab[1+(v&1)]
__global__ __launch_bounds__(256) void level_kernel(float* __restrict__ tab, int l) {
  __shared__ float P[64][65];
  __shared__ float Bs[64][64];
  const int t = threadIdx.x;
  const int v = blockIdx.x;
  const float* A = tab + (size_t)((1 << (l - 1)) - 1 + (v >> 1)) * 4096;
  const float* Bg = tab + (size_t)(1 + (v & 1)) * 4096;
  float* C = tab + (size_t)((1 << l) - 1 + v) * 4096;
#pragma unroll
  for (int i = 0; i < 16; ++i) {
    const int idx = (i << 8) | t;
    P[idx >> 6][idx & 63] = A[idx];
    Bs[idx >> 6][idx & 63] = Bg[idx];
  }
  __syncthreads();
  float acc[4][4] = {};
  mm64(P, Bs, acc, t);
  const int r0 = (t >> 4) << 2, c0 = (t & 15) << 2;
#pragma unroll
  for (int i = 0; i < 4; ++i)
    *reinterpret_cast<float4*>(&C[(r0 + i) * 64 + c0]) =
        make_float4(acc[i][0], acc[i][1], acc[i][2], acc[i][3]);
}

// maps[n] = T[prefix(slots 0..5)] @ T[suffix(slots 6..11)]
__global__ __launch_bounds__(256) void maps_kernel(const int* __restrict__ pw,
                                                   const float* __restrict__ tab,
                                                   float* __restrict__ out) {
  __shared__ float P[64][65];
  __shared__ float Bs[64][64];
  const int t = threadIdx.x;
  const int n = blockIdx.x;
  int v1 = 0, l1 = 0, v2 = 0, l2 = 0;
#pragma unroll
  for (int tt = 0; tt < 6; ++tt) {
    const int w = pw[n * TLEN + tt];
    if (w < 2) { v1 = (v1 << 1) | w; ++l1; }
  }
#pragma unroll
  for (int tt = 6; tt < 12; ++tt) {
    const int w = pw[n * TLEN + tt];
    if (w < 2) { v2 = (v2 << 1) | w; ++l2; }
  }
  const float* A = tab + (size_t)((1 << l1) - 1 + v1) * 4096;
  const float* Bg = tab + (size_t)((1 << l2) - 1 + v2) * 4096;
#pragma unroll
  for (int i = 0; i < 16; ++i) {
    const int idx = (i << 8) | t;
    P[idx >> 6][idx & 63] = A[idx];
    Bs[idx >> 6][idx & 63] = Bg[idx];
  }
  __syncthreads();
  float acc[4][4] = {};
  mm64(P, Bs, acc, t);
  float* C = out + (size_t)n * 4096;
  const int r0 = (t >> 4) << 2, c0 = (t & 15) << 2;
#pragma unroll
  for (int i = 0; i < 4; ++i)
    *reinterpret_cast<float4*>(&C[(r0 + i) * 64 + c0]) =
        make_float4(acc[i][0], acc[i][1], acc[i][2], acc[i][3]);
}

// Pack each padded path word into a left-aligned 2-bit-per-digit key.
__global__ __launch_bounds__(256) void keys_kernel(const int* __restrict__ pw,
                                                   unsigned* __restrict__ keys) {
  const int n = blockIdx.x * 256 + threadIdx.x;
  if (n >= NPOS) return;
  unsigned k = 0;
#pragma unroll
  for (int tt = 0; tt < TLEN; ++tt) k = (k << 2) | (unsigned)pw[n * TLEN + tt];
  keys[n] = k << 8;  // 24 meaningful bits left-aligned in 32
}

__device__ __forceinline__ float step_val(unsigned a, unsigned b) {
  const unsigned x = a ^ b;
  const int cp = x ? (__builtin_clz(x) >> 1) : TLEN;
  return (float)(2 * TLEN - 2 * cp);
}

// steps[i][j] = 24 - 2*commonPrefixLen  (lens are all 12 since pm is all-True)
__global__ __launch_bounds__(256) void steps_kernel(const unsigned* __restrict__ keys,
                                                    float* __restrict__ out) {
  const int i = blockIdx.y;
  const int j0 = (blockIdx.x * 256 + threadIdx.x) << 2;
  const unsigned ki = keys[i];
  const uint4 kj = *reinterpret_cast<const uint4*>(&keys[j0]);
  float4 r;
  r.x = step_val(ki, kj.x);
  r.y = step_val(ki, kj.y);
  r.z = step_val(ki, kj.z);
  r.w = step_val(ki, kj.w);
  *reinterpret_cast<float4*>(&out[(size_t)i * NPOS + j0]) = r;
}

extern "C" void kernel_launch(void* const* d_in, const int* in_sizes, int n_in,
                              void* d_out, int out_size, void* d_ws, size_t ws_size,
                              hipStream_t stream) {
  const float* raw = (const float*)d_in[0];     // (17, 64, 64) f32
  const int* pw = (const int*)d_in[1];          // (4096, 12) i32
  float* out = (float*)d_out;                   // maps (16.7M) then steps (16.7M)
  float* tab = (float*)d_ws;                    // 127 * 4096 floats (~2.08 MB)
  unsigned* keys = (unsigned*)(tab + (size_t)127 * 4096);

  expm_kernel<<<2, 256, 0, stream>>>(raw, tab);                 // tab[0..2]
  for (int l = 2; l <= 6; ++l)
    level_kernel<<<(1 << l), 256, 0, stream>>>(tab, l);         // tab[3..126]
  maps_kernel<<<NPOS, 256, 0, stream>>>(pw, tab, out);
  keys_kernel<<<NPOS / 256, 256, 0, stream>>>(pw, keys);
  steps_kernel<<<dim3(NPOS / 1024, NPOS), 256, 0, stream>>>(keys, out + (size_t)NPOS * 4096);
}

// Round 2
// 185.523 us; speedup vs baseline: 1.3682x; 1.3682x over previous
//
#include <hip/hip_runtime.h>

// UnitaryBranching on MI355X.
// maps[n] = T[prefix] @ T[suffix] over a 127-entry binary-product table of
// ext = [P0^T, P1^T, I, I]; table+maps in bf16 MFMA (threshold 0.48 in bf16
// space gives 10x margin). expm stays f32 (squarings amplify error 2^8).
// steps[i][j] = 24 - 2*commonPrefixLen(padded words), exact, fused with expm.

#define NPOS 4096
#define TLEN 12

typedef __attribute__((ext_vector_type(8))) short short8;
typedef __attribute__((ext_vector_type(4))) float f32x4;

__device__ __forceinline__ unsigned short f2bf(float f) {
  union { float f; unsigned u; } v; v.f = f;
  unsigned r = v.u + 0x7fffu + ((v.u >> 16) & 1u);  // RNE
  return (unsigned short)(r >> 16);
}

// C += P @ B over full K=64. P padded [64][68] (row = 272B, 16B-aligned float4,
// 16-lane broadcast on A-reads), B [64][64] (row-chunk float4, 2-way = free).
// Per thread: 4x4 tile, all loads b128.
__device__ __forceinline__ void mm64v(const float P[64][68], const float B[64][64],
                                      float acc[4][4], int r0, int c0) {
#pragma unroll 4
  for (int k0 = 0; k0 < 64; k0 += 4) {
    float a[4][4], bb[4][4];
#pragma unroll
    for (int i = 0; i < 4; ++i) {
      const float4 t = *reinterpret_cast<const float4*>(&P[r0 + i][k0]);
      a[i][0] = t.x; a[i][1] = t.y; a[i][2] = t.z; a[i][3] = t.w;
    }
#pragma unroll
    for (int kk = 0; kk < 4; ++kk) {
      const float4 t = *reinterpret_cast<const float4*>(&B[k0 + kk][c0]);
      bb[kk][0] = t.x; bb[kk][1] = t.y; bb[kk][2] = t.z; bb[kk][3] = t.w;
    }
#pragma unroll
    for (int i = 0; i < 4; ++i)
#pragma unroll
      for (int kk = 0; kk < 4; ++kk)
#pragma unroll
        for (int j = 0; j < 4; ++j) acc[i][j] += a[i][kk] * bb[kk][j];
  }
}

__device__ __forceinline__ float step_val(unsigned a, unsigned b) {
  const unsigned x = a ^ b;
  const int cp = x ? (__builtin_clz(x) >> 1) : TLEN;
  return (float)(2 * TLEN - 2 * cp);
}

// blocks 0,1: expm (order-5 Horner + 8 squarings, f32 in LDS), writes bf16
// table entries 0..2 in dual layout. blocks 2..: steps tiles (write-bound,
// hides under the 2-CU expm chain).
__global__ __launch_bounds__(256) void expm_steps_kernel(
    const float* __restrict__ raw, const unsigned* __restrict__ keys,
    unsigned short* __restrict__ tabR, unsigned short* __restrict__ tabT,
    float* __restrict__ steps_out) {
  __shared__ float P[64][68];
  __shared__ float Bs[64][64];
  const int t = threadIdx.x;

  if (blockIdx.x >= 2) {  // ---- steps ----
    const int b = (int)blockIdx.x - 2;
    const int i = b >> 2;
    const int j0 = ((b & 3) << 10) | (t << 2);
    const unsigned ki = keys[i];
    const uint4 kj = *reinterpret_cast<const uint4*>(&keys[j0]);
    float4 r;
    r.x = step_val(ki, kj.x);
    r.y = step_val(ki, kj.y);
    r.z = step_val(ki, kj.z);
    r.w = step_val(ki, kj.w);
    *reinterpret_cast<float4*>(&steps_out[(size_t)i * NPOS + j0]) = r;
    return;
  }

  // ---- expm for matrix d ----
  const int d = blockIdx.x;
  const int r0 = (t >> 4) << 2, c0 = (t & 15) << 2;
  // P = (raw - raw^T)/2^8 ; Bs = I + P/5  (Horner k=5 step with E=I is free)
#pragma unroll
  for (int i = 0; i < 16; ++i) {
    const int idx = (i << 8) | t;
    const int r = idx >> 6, c = idx & 63;
    const float a = (raw[d * 4096 + r * 64 + c] - raw[d * 4096 + c * 64 + r]) * (1.0f / 256.0f);
    P[r][c] = a;
    Bs[r][c] = ((r == c) ? 1.0f : 0.0f) + a * 0.2f;
  }
  __syncthreads();

  // Horner k=4..1: E = I + (A@E)/k   (A const in P)
  for (int k = 4; k >= 1; --k) {
    float acc[4][4] = {};
    mm64v(P, Bs, acc, r0, c0);
    __syncthreads();  // all reads of Bs done
    const float inv = 1.0f / (float)k;
#pragma unroll
    for (int i = 0; i < 4; ++i)
#pragma unroll
      for (int j = 0; j < 4; ++j) {
        const int r = r0 + i, c = c0 + j;
        Bs[r][c] = ((r == c) ? 1.0f : 0.0f) + acc[i][j] * inv;
      }
    __syncthreads();
  }

  // 8 squarings: E = E @ E
  for (int s = 0; s < 8; ++s) {
#pragma unroll
    for (int i = 0; i < 16; ++i) {
      const int idx = (i << 8) | t;
      P[idx >> 6][idx & 63] = Bs[idx >> 6][idx & 63];
    }
    __syncthreads();
    float acc[4][4] = {};
    mm64v(P, Bs, acc, r0, c0);
    __syncthreads();  // all reads of Bs done
#pragma unroll
    for (int i = 0; i < 4; ++i)
      *reinterpret_cast<float4*>(&Bs[r0 + i][c0]) =
          make_float4(acc[i][0], acc[i][1], acc[i][2], acc[i][3]);
    __syncthreads();
  }

  // ext[d] = E^T:  tabR[1+d] = E^T (row-major, A-role), tabT[1+d] = E (B-role)
  unsigned short* oR = tabR + (size_t)(1 + d) * 4096;
  unsigned short* oT = tabT + (size_t)(1 + d) * 4096;
#pragma unroll
  for (int i = 0; i < 16; ++i) {
    const int idx = (i << 8) | t;
    const int r = idx >> 6, c = idx & 63;
    oR[idx] = f2bf(Bs[c][r]);
    oT[idx] = f2bf(Bs[r][c]);
  }
  if (d == 0) {  // entry 0 = I (both layouts)
#pragma unroll
    for (int i = 0; i < 16; ++i) {
      const int idx = (i << 8) | t;
      const int r = idx >> 6, c = idx & 63;
      const unsigned short v = (r == c) ? (unsigned short)0x3F80 : (unsigned short)0;
      tabR[idx] = v;
      tabT[idx] = v;
    }
  }
}

// Shared MFMA core: C(64x64,f32) = X(row-major bf16) @ Y^T(row-major bf16 = Y
// col-major). Wave wv owns rows 16wv..16wv+15; k-map kappa(q,g,b)=32q+8g+b is a
// bijection applied identically to A and B frags (layout-safe).
__device__ __forceinline__ void mfma64(const unsigned short* __restrict__ X,
                                       const unsigned short* __restrict__ Yt,
                                       f32x4 acc[4], int wv, int l) {
  const int row = l & 15, g = l >> 4;
  short8 a[2], b[4][2];
#pragma unroll
  for (int q = 0; q < 2; ++q)
    a[q] = *reinterpret_cast<const short8*>(X + (((16 * wv + row) << 6) | (q << 5) | (g << 3)));
#pragma unroll
  for (int c = 0; c < 4; ++c)
#pragma unroll
    for (int q = 0; q < 2; ++q)
      b[c][q] = *reinterpret_cast<const short8*>(Yt + (((16 * c + row) << 6) | (q << 5) | (g << 3)));
#pragma unroll
  for (int c = 0; c < 4; ++c) {
    acc[c] = __builtin_amdgcn_mfma_f32_16x16x32_bf16(a[0], b[c][0], acc[c], 0, 0, 0);
    acc[c] = __builtin_amdgcn_mfma_f32_16x16x32_bf16(a[1], b[c][1], acc[c], 0, 0, 0);
  }
}

// Build table levels via entry-pair products, dual bf16 output.
// mode 0: l2 (4 blocks); mode 1: l3(8)+l4(16); mode 2: l5(32)+l6(64).
__global__ __launch_bounds__(256) void pair_kernel(unsigned short* __restrict__ tabR,
                                                   unsigned short* __restrict__ tabT,
                                                   int mode) {
  const int bid = blockIdx.x;
  int xe, ye, oe;
  if (mode == 0) {
    xe = 1 + (bid >> 1); ye = 1 + (bid & 1); oe = 3 + bid;
  } else if (mode == 1) {
    if (bid < 8) { xe = 3 + (bid >> 1); ye = 1 + (bid & 1); oe = 7 + bid; }
    else { const int v = bid - 8; xe = 3 + (v >> 2); ye = 3 + (v & 3); oe = 15 + v; }
  } else {
    if (bid < 32) { xe = 15 + (bid >> 1); ye = 1 + (bid & 1); oe = 31 + bid; }
    else { const int v = bid - 32; xe = 15 + (v >> 2); ye = 3 + (v & 3); oe = 63 + v; }
  }
  const int wv = threadIdx.x >> 6, l = threadIdx.x & 63;
  f32x4 acc[4] = {f32x4{0,0,0,0}, f32x4{0,0,0,0}, f32x4{0,0,0,0}, f32x4{0,0,0,0}};
  mfma64(tabR + (size_t)xe * 4096, tabT + (size_t)ye * 4096, acc, wv, l);
  unsigned short* oR = tabR + (size_t)oe * 4096;
  unsigned short* oT = tabT + (size_t)oe * 4096;
  const int row = l & 15, g = l >> 4;
#pragma unroll
  for (int c = 0; c < 4; ++c)
#pragma unroll
    for (int r = 0; r < 4; ++r) {
      const unsigned short v = f2bf(acc[c][r]);
      const int rr = 16 * wv + 4 * g + r, cc = 16 * c + row;
      oR[rr * 64 + cc] = v;
      oT[cc * 64 + rr] = v;
    }
}

// maps[n] = T[prefix] @ T[suffix], f32 out. No LDS, frags from L2-hot table.
__global__ __launch_bounds__(256) void maps_kernel(const int* __restrict__ pw,
                                                   const unsigned short* __restrict__ tabR,
                                                   const unsigned short* __restrict__ tabT,
                                                   float* __restrict__ out) {
  const int n = blockIdx.x;
  int v1 = 0, l1 = 0, v2 = 0, l2 = 0;
#pragma unroll
  for (int tt = 0; tt < 6; ++tt) {
    const int w = pw[n * TLEN + tt];
    if (w < 2) { v1 = (v1 << 1) | w; ++l1; }
  }
#pragma unroll
  for (int tt = 6; tt < 12; ++tt) {
    const int w = pw[n * TLEN + tt];
    if (w < 2) { v2 = (v2 << 1) | w; ++l2; }
  }
  const int wv = threadIdx.x >> 6, l = threadIdx.x & 63;
  f32x4 acc[4] = {f32x4{0,0,0,0}, f32x4{0,0,0,0}, f32x4{0,0,0,0}, f32x4{0,0,0,0}};
  mfma64(tabR + (size_t)((1 << l1) - 1 + v1) * 4096,
         tabT + (size_t)((1 << l2) - 1 + v2) * 4096, acc, wv, l);
  float* O = out + (size_t)n * 4096;
  const int row = l & 15, g = l >> 4;
#pragma unroll
  for (int c = 0; c < 4; ++c)
#pragma unroll
    for (int r = 0; r < 4; ++r)
      O[((16 * wv + 4 * g + r) << 6) | (16 * c + row)] = acc[c][r];
}

__global__ __launch_bounds__(256) void keys_kernel(const int* __restrict__ pw,
                                                   unsigned* __restrict__ keys) {
  const int n = blockIdx.x * 256 + threadIdx.x;
  unsigned k = 0;
#pragma unroll
  for (int tt = 0; tt < TLEN; ++tt) k = (k << 2) | (unsigned)pw[n * TLEN + tt];
  keys[n] = k << 8;
}

extern "C" void kernel_launch(void* const* d_in, const int* in_sizes, int n_in,
                              void* d_out, int out_size, void* d_ws, size_t ws_size,
                              hipStream_t stream) {
  const float* raw = (const float*)d_in[0];  // (17,64,64) f32
  const int* pw = (const int*)d_in[1];       // (4096,12) i32
  float* out = (float*)d_out;                // maps then steps, f32

  unsigned short* tabR = (unsigned short*)d_ws;            // 127 * 8KB
  unsigned short* tabT = tabR + (size_t)127 * 4096;        // 127 * 8KB
  unsigned* keys = (unsigned*)((char*)d_ws + (2u << 20));  // 16KB @ +2MB

  keys_kernel<<<NPOS / 256, 256, 0, stream>>>(pw, keys);
  expm_steps_kernel<<<2 + NPOS * 4, 256, 0, stream>>>(raw, keys, tabR, tabT,
                                                      out + (size_t)NPOS * 4096);
  pair_kernel<<<4, 256, 0, stream>>>(tabR, tabT, 0);
  pair_kernel<<<24, 256, 0, stream>>>(tabR, tabT, 1);
  pair_kernel<<<96, 256, 0, stream>>>(tabR, tabT, 2);
  maps_kernel<<<NPOS, 256, 0, stream>>>(pw, tabR, tabT, out);
}